// Round 3
// baseline (881.502 us; speedup 1.0000x reference)
//
#include <hip/hip_runtime.h>
#include <hip/hip_fp16.h>

// GCN 2-layer, N=100000, F=64, H=128, O=100, out [N,1] fp32.
// out = agg(relu(agg(x)@W1 + b1) . (W2@Wl)) + (b2@Wl + bl)
// Pipeline: partA multi-splits edges into padded dst-buckets; partB computes
// degrees/dinv, 13-bin sorts each bucket by SRC-TILE (8192 srcs = 1MB of y per
// tile), emits fp16 pre-scaled y. fused1: one block per bucket, all-resident
// grid walks tiles in lock-step (per-XCD L2 holds the live tile); gathers use
// the 8-edge x 8-uint4-col wave shape; accumulate into LDS f32 at stride 72 via
// unsafeAtomicAdd -> native ds_add_f32 (plain atomicAdd(float) compiles to a
// ~300-cycle CAS loop without -munsafe-fp-atomics: that was rounds 1-2's 750us).
// out: per-bucket LDS scatter of zz (L2-resident), also unsafeAtomicAdd.

#define N_NODES 100000
#define F_IN 64
#define HID 128
#define OUT2 100
#define BSHIFT 8
#define BNODES 256
#define NBUCKETS ((N_NODES + BNODES - 1) / BNODES)  // 391
#define SCAP 4608   // bucket capacity: mean 4096 + 8 sigma (sigma=64)
#define ACHUNK 4096 // edges per partA block
#define NB_PAD 512
#define SENTB 0xFFFFu
#define TSHIFT 13   // src tile = src >> 13 (8192 srcs = 1 MB of y per tile)
#define NTILES 13   // ceil(100000 / 8192)
#define RSTRIDE 72  // accf floats per node row: 8 blocks x 9 (8 data + 1 pad)

typedef _Float16 half8 __attribute__((ext_vector_type(8)));
typedef float f32x4 __attribute__((ext_vector_type(4)));

static __device__ __forceinline__ half8 as_half8(uint4 u) {
    union { uint4 u; half8 h; } x; x.u = u; return x.h;
}

// Blocks 0..7: pack W1 (MFMA B-layout, fp16 hi+lo).
// Block 8: v = W2@Wl, c = b2.Wl + bl, init bcur[b] = b*SCAP.
__global__ __launch_bounds__(256) void prep_kernel(
    const float* __restrict__ W1, const float* __restrict__ W2,
    const float* __restrict__ b2, const float* __restrict__ Wl,
    const float* __restrict__ bl,
    float* __restrict__ v, float* __restrict__ c, uint4* __restrict__ Wpk,
    int* __restrict__ bcur) {
    int t = threadIdx.x;
    if (blockIdx.x < 8) {
        // idx: bit10 = part (0=hi,1=lo), bits9..7 = cb, bit6 = kf, bits5..0 = lane
        int idx = blockIdx.x * 256 + t;
        int lane2 = idx & 63;
        int kf    = (idx >> 6) & 1;
        int cb    = (idx >> 7) & 7;
        int part  = (idx >> 10) & 1;
        union { uint4 u; unsigned short s[8]; } pk;
        #pragma unroll
        for (int j = 0; j < 8; ++j) {
            int k    = kf * 32 + (lane2 >> 4) * 8 + j;
            int colg = cb * 16 + (lane2 & 15);
            float w = W1[k * HID + colg];
            __half h = __float2half_rn(w);
            if (part) h = __float2half_rn(w - __half2float(h));
            pk.s[j] = __half_as_ushort(h);
        }
        Wpk[idx] = pk.u;
    } else {
        bcur[t] = t * SCAP;
        bcur[t + 256] = (t + 256) * SCAP;
        if (t < HID) {
            float acc = 0.f;
            for (int k = 0; k < OUT2; ++k) acc += W2[t * OUT2 + k] * Wl[k];
            v[t] = acc;
        } else if (t == HID) {
            float acc = bl[0];
            for (int k = 0; k < OUT2; ++k) acc += b2[k] * Wl[k];
            *c = acc;
        }
    }
}

// Pass A: LDS multi-split into padded dst-buckets; ONE reserve-atomic per
// bucket per block. Packed entry = (src<<8) | (dst&255).
__global__ __launch_bounds__(256) void partA_kernel(
    const int* __restrict__ src, const int* __restrict__ dst,
    int* __restrict__ bcur, unsigned int* __restrict__ ebuf, int E) {
    __shared__ unsigned int stage[ACHUNK];       // 16 KB
    __shared__ unsigned short sb[ACHUNK];        // 8 KB
    __shared__ int hist[NB_PAD];
    __shared__ int ocnt[NB_PAD];
    __shared__ int gbase[NB_PAD];
    __shared__ int cnt2[NB_PAD];
    int t = threadIdx.x;
    int base = blockIdx.x * ACHUNK;
    int total = E - base; if (total > ACHUNK) total = ACHUNK;

    hist[t] = 0; hist[t + 256] = 0;
    cnt2[t] = 0; cnt2[t + 256] = 0;
    __syncthreads();

    unsigned int pe[16];
    unsigned short bk[16];
    #pragma unroll
    for (int k = 0; k < 16; ++k) {
        int e = base + k * 256 + t;
        if (e < E) {
            int s = src[e], d = dst[e];
            pe[k] = ((unsigned int)s << 8) | (unsigned int)(d & (BNODES - 1));
            bk[k] = (unsigned short)(d >> BSHIFT);
            atomicAdd(&hist[bk[k]], 1);
        } else {
            bk[k] = SENTB;
        }
    }
    __syncthreads();
    ocnt[t] = hist[t]; ocnt[t + 256] = hist[t + 256];
    __syncthreads();
    for (int off = 1; off < NB_PAD; off <<= 1) {
        int v0 = (t >= off) ? hist[t - off] : 0;
        int v1 = hist[t + 256 - off];
        __syncthreads();
        hist[t] += v0; hist[t + 256] += v1;
        __syncthreads();
    }
    #pragma unroll
    for (int i = 0; i < 2; ++i) {
        int b = (t + i * 256 + blockIdx.x * 131) & (NB_PAD - 1);
        int cc = ocnt[b];
        if (cc > 0 && b < NBUCKETS) gbase[b] = atomicAdd(&bcur[b], cc);
    }
    __syncthreads();
    #pragma unroll
    for (int k = 0; k < 16; ++k) {
        if (bk[k] != SENTB) {
            int b = bk[k];
            int pos = (hist[b] - ocnt[b]) + atomicAdd(&cnt2[b], 1);
            stage[pos] = pe[k];
            sb[pos] = (unsigned short)b;
        }
    }
    __syncthreads();
    #pragma unroll
    for (int k = 0; k < 16; ++k) {
        int idx = k * 256 + t;
        if (idx < total) {
            int b = sb[idx];
            int lo = hist[b] - ocnt[b];
            ebuf[gbase[b] + (idx - lo)] = stage[idx];
        }
    }
}

// Pass B: per bucket: dl-histogram -> dinv; 13-bin counting sort by src-tile
// (keeps FULL entries (src<<8|dl)); emits fp16 pre-scaled y rows.
__global__ __launch_bounds__(256) void partB_kernel(
    const int* __restrict__ bcur, unsigned int* __restrict__ csr,
    float* __restrict__ dinv,
    const float4* __restrict__ x4, __half2* __restrict__ y2, int n) {
    __shared__ int lcnt[BNODES];
    __shared__ float sdinv[BNODES];
    __shared__ int tcnt[16];
    __shared__ int tstart[16];
    __shared__ int tcur[16];
    __shared__ unsigned int sbuf[SCAP];
    int b = blockIdx.x, t = threadIdx.x;
    int node0 = b << BSHIFT;
    int nlocal = min(BNODES, n - node0);
    int base = b * SCAP;
    int cnt = bcur[b] - base;
    lcnt[t] = 0;
    if (t < 16) tcnt[t] = 0;
    __syncthreads();
    unsigned int er[SCAP / 256];
    #pragma unroll
    for (int k = 0; k < SCAP / 256; ++k) {
        int idx = k * 256 + t;
        er[k] = (idx < cnt) ? csr[base + idx] : 0xFFFFFFFFu;
        if (er[k] != 0xFFFFFFFFu) {
            atomicAdd(&lcnt[er[k] & (BNODES - 1)], 1);
            atomicAdd(&tcnt[er[k] >> (8 + TSHIFT)], 1);
        }
    }
    __syncthreads();
    int own = lcnt[t];
    sdinv[t] = rsqrtf((float)own + 1.0f);
    if (t < nlocal) dinv[node0 + t] = sdinv[t];
    if (t == 0) {
        int s = 0;
        #pragma unroll
        for (int i = 0; i < NTILES; ++i) { tstart[i] = s; s += tcnt[i]; }
    }
    __syncthreads();
    if (t < NTILES) tcur[t] = tstart[t];
    __syncthreads();
    #pragma unroll
    for (int k = 0; k < SCAP / 256; ++k) {
        unsigned int e = er[k];
        if (e != 0xFFFFFFFFu) {
            int p = atomicAdd(&tcur[e >> (8 + TSHIFT)], 1);
            sbuf[p] = e;
        }
    }
    __syncthreads();
    for (int idx = t; idx < cnt; idx += 256) csr[base + idx] = sbuf[idx];
    // y emission (dinv[src]-prescaled fp16 rows)
    for (int i = t; i < nlocal * 16; i += 256) {
        int nl = i >> 4;
        int gi = (node0 + nl) * 16 + (i & 15);
        float di = sdinv[nl];
        float4 xv = x4[gi];
        y2[2 * gi]     = __floats2half2_rn(xv.x * di, xv.y * di);
        y2[2 * gi + 1] = __floats2half2_rn(xv.z * di, xv.w * di);
    }
}

// Fused layer 1: block = bucket (256 dst nodes). Edges are tile-sorted; the
// all-resident grid walks tiles in lock-step so the live y-tile stays L2-hot.
// Gather shape: 64 lanes = 8 edges (q=lane>>3) x 8 uint4 cols (col=lane&7);
// one VMEM instr touches 8 distinct 128B rows, 8 instrs issued back-to-back
// => 64 lines in flight per wave. Scatter into accf at stride 72 (col*9+j):
// bank = (8*dl + 9*col + j) & 31 -> ~2-way (free). unsafeAtomicAdd -> ds_add_f32.
__global__ __launch_bounds__(256) void fused1_kernel(
    const uint4* __restrict__ y4, const unsigned short* __restrict__ yh,
    const unsigned int* __restrict__ csr, const int* __restrict__ bcur,
    const float* __restrict__ dinv, const uint4* __restrict__ Wpk,
    const float* __restrict__ b1, const float* __restrict__ v,
    float* __restrict__ zz, int n) {
    __shared__ float accf[BNODES * RSTRIDE];   // 72 KB -> 2 blocks/CU, all resident
    int t = threadIdx.x;
    int lane = t & 63, wave = t >> 6;
    int q = lane >> 3, col = lane & 7;
    int b = blockIdx.x;
    int node0 = b << BSHIFT;
    int nlocal = min(BNODES, n - node0);
    int base = b * SCAP;
    int end = bcur[b];
    int cnt = end - base;

    // self-loop init: acc[r][f] = y[node0+r][f] (already dinv[src]-scaled)
    for (int r = wave; r < BNODES; r += 4) {
        float vv = 0.f;
        if (r < nlocal) vv = __half2float(__ushort_as_half(yh[(node0 + r) * 64 + lane]));
        accf[r * RSTRIDE + (lane >> 3) * 9 + (lane & 7)] = vv;
    }
    __syncthreads();

    // edge accumulation: wave handles 64-edge chunks (stride 256 across waves).
    int nrounds = (cnt + 255) >> 8;
    for (int r = 0; r < nrounds; ++r) {
        int bb = base + r * 256 + wave * 64;
        int eidx = bb + lane;
        unsigned int ee = (eidx < end) ? csr[eidx] : 0xFFFFFFFFu;
        uint4 u[8];
        int dl[8];
        #pragma unroll
        for (int g = 0; g < 8; ++g) {
            unsigned int e = __shfl(ee, g * 8 + q, 64);
            bool valid = (e != 0xFFFFFFFFu);
            int srow = valid ? (int)(e >> 8) : 0;
            dl[g] = (int)(e & 255u);           // 255 for invalid: safe addr
            u[g] = y4[srow * 8 + col];
            if (!valid) u[g] = (uint4){0u, 0u, 0u, 0u};  // add 0.0f = no-op
        }
        #pragma unroll
        for (int g = 0; g < 8; ++g) {
            const __half* hp = (const __half*)&u[g];
            float* rowp = &accf[dl[g] * RSTRIDE + col * 9];
            #pragma unroll
            for (int j = 0; j < 8; ++j)
                unsafeAtomicAdd(&rowp[j], __half2float(hp[j]));
        }
    }
    __syncthreads();

    // MFMA + epilogue: each wave handles 4 sub-tiles of 16 nodes.
    int mm = lane & 15, kq = lane >> 4;
    for (int i = 0; i < 4; ++i) {
        int st = wave * 4 + i;
        int row = st * 16 + mm;
        float di = (row < nlocal) ? dinv[node0 + row] : 0.f;
        const float* ap = &accf[row * RSTRIDE];
        half8 A0, A1;
        #pragma unroll
        for (int j = 0; j < 8; ++j) {
            A0[j] = (_Float16)(di * ap[kq * 9 + j]);
            A1[j] = (_Float16)(di * ap[(4 + kq) * 9 + j]);
        }
        f32x4 acc[8];
        #pragma unroll
        for (int cb = 0; cb < 8; ++cb) acc[cb] = (f32x4){0.f, 0.f, 0.f, 0.f};
        #pragma unroll
        for (int cb = 0; cb < 8; ++cb) {
            half8 bh0 = as_half8(Wpk[(cb * 2 + 0) * 64 + lane]);
            half8 bh1 = as_half8(Wpk[(cb * 2 + 1) * 64 + lane]);
            half8 bl0 = as_half8(Wpk[1024 + (cb * 2 + 0) * 64 + lane]);
            half8 bl1 = as_half8(Wpk[1024 + (cb * 2 + 1) * 64 + lane]);
            acc[cb] = __builtin_amdgcn_mfma_f32_16x16x32_f16(A0, bh0, acc[cb], 0, 0, 0);
            acc[cb] = __builtin_amdgcn_mfma_f32_16x16x32_f16(A1, bh1, acc[cb], 0, 0, 0);
            acc[cb] = __builtin_amdgcn_mfma_f32_16x16x32_f16(A0, bl0, acc[cb], 0, 0, 0);
            acc[cb] = __builtin_amdgcn_mfma_f32_16x16x32_f16(A1, bl1, acc[cb], 0, 0, 0);
        }
        float zp[4] = {0.f, 0.f, 0.f, 0.f};
        #pragma unroll
        for (int cb = 0; cb < 8; ++cb) {
            int colg = cb * 16 + mm;
            float bb1 = b1[colg], vv = v[colg];
            #pragma unroll
            for (int rr = 0; rr < 4; ++rr) {
                float h = acc[cb][rr] + bb1;
                h = fmaxf(h, 0.f);
                zp[rr] += h * vv;
            }
        }
        #pragma unroll
        for (int off = 1; off < 16; off <<= 1) {
            #pragma unroll
            for (int rr = 0; rr < 4; ++rr) zp[rr] += __shfl_xor(zp[rr], off, 64);
        }
        if (mm == 0) {
            int nb = st * 16 + kq * 4;
            #pragma unroll
            for (int rr = 0; rr < 4; ++rr)
                if (nb + rr < nlocal)
                    zz[node0 + nb + rr] = dinv[node0 + nb + rr] * zp[rr];
        }
    }
}

// Layer 2 (collapsed): per-bucket LDS scatter of zz (zz = 400KB, L2-resident).
// out[i] = c + dinv[i]*(zz[i] + sum_in zz[s]).
__global__ __launch_bounds__(256) void out_kernel(
    const int* __restrict__ bcur, const unsigned int* __restrict__ csr,
    const float* __restrict__ dinv, const float* __restrict__ zz,
    const float* __restrict__ c, float* __restrict__ out, int n) {
    __shared__ float acc2[BNODES];
    int b = blockIdx.x, t = threadIdx.x;
    int node0 = b << BSHIFT;
    int nlocal = min(BNODES, n - node0);
    int base = b * SCAP;
    int cnt = bcur[b] - base;
    acc2[t] = 0.f;
    __syncthreads();
    unsigned int er[SCAP / 256];
    #pragma unroll
    for (int k = 0; k < SCAP / 256; ++k) {
        int idx = k * 256 + t;
        er[k] = (idx < cnt) ? csr[base + idx] : 0xFFFFFFFFu;
    }
    #pragma unroll
    for (int k = 0; k < SCAP / 256; ++k) {
        if (er[k] != 0xFFFFFFFFu) {
            float z = zz[er[k] >> 8];
            unsafeAtomicAdd(&acc2[er[k] & (BNODES - 1)], z);
        }
    }
    __syncthreads();
    if (t < nlocal) {
        int node = node0 + t;
        out[node] = c[0] + dinv[node] * (acc2[t] + zz[node]);
    }
}

extern "C" void kernel_launch(void* const* d_in, const int* in_sizes, int n_in,
                              void* d_out, int out_size, void* d_ws, size_t ws_size,
                              hipStream_t stream) {
    const float* x  = (const float*)d_in[0];
    const int*   ei = (const int*)d_in[1];
    const float* W1 = (const float*)d_in[2];
    const float* b1 = (const float*)d_in[3];
    const float* W2 = (const float*)d_in[4];
    const float* b2 = (const float*)d_in[5];
    const float* Wl = (const float*)d_in[6];
    const float* bl = (const float*)d_in[7];
    float* out = (float*)d_out;

    int E = in_sizes[1] / 2;
    const int* src = ei;
    const int* dst = ei + E;

    float* ws      = (float*)d_ws;
    float* dinv    = ws;                        // N
    float* zz      = dinv + N_NODES;            // N
    float* v       = zz + N_NODES;              // 128
    float* c       = v + HID;                   // 4
    int*   bcur    = (int*)(c + 4);             // 512
    int*   csr     = bcur + 512;                // NBUCKETS*SCAP
    uint4* Wpk     = (uint4*)(csr + (size_t)NBUCKETS * SCAP);  // 2048 uint4
    __half* y      = (__half*)((float*)Wpk + 8192);            // N*64 halves

    int nchunks = (E + ACHUNK - 1) / ACHUNK;   // 391

    prep_kernel<<<9, 256, 0, stream>>>(W1, W2, b2, Wl, bl, v, c, Wpk, bcur);
    partA_kernel<<<nchunks, 256, 0, stream>>>(src, dst, bcur, (unsigned int*)csr, E);
    partB_kernel<<<NBUCKETS, 256, 0, stream>>>(
        bcur, (unsigned int*)csr, dinv, (const float4*)x, (__half2*)y, N_NODES);
    fused1_kernel<<<NBUCKETS, 256, 0, stream>>>(
        (const uint4*)y, (const unsigned short*)y, (const unsigned int*)csr,
        bcur, dinv, Wpk, b1, v, zz, N_NODES);
    out_kernel<<<NBUCKETS, 256, 0, stream>>>(
        bcur, (const unsigned int*)csr, dinv, zz, c, out, N_NODES);
}

// Round 4
// 240.269 us; speedup vs baseline: 3.6688x; 3.6688x over previous
//
#include <hip/hip_runtime.h>
#include <hip/hip_fp16.h>

// GCN 2-layer, N=100000, F=64, H=128, O=100, out [N,1] fp32.
// out = agg(relu(agg(x)@W1 + b1) . (W2@Wl)) + (b2@Wl + bl)
// partA: multi-split edges into padded dst-buckets (entry = src<<8|dl).
// partB: per bucket: dl-histogram -> dinv + rs/re, node-major dl-sort of csr,
//        PLUS tile-major perm (ushort positions; tile = src>>13 = 1MB of y),
//        emits fp16 pre-scaled y.
// fused1: one 391-block all-resident grid; walks edges in perm (tile) order so
//        the live 1MB y-tile stays L2-hot per XCD (round1-3 verified: 92MB
//        fetch = per-XCD reuse floor); accumulates into LDS **int fixed-point**
//        via native ds_add_u32 (fp32 LDS atomicAdd = ~440cyc CAS loop — that
//        was rounds 1-3's 750us; int LDS atomics are ~5cyc, proven in partA/B).
// out: round-0 register-gather version (no atomics), csr entry >>8.

#define N_NODES 100000
#define F_IN 64
#define HID 128
#define OUT2 100
#define BSHIFT 8
#define BNODES 256
#define NBUCKETS ((N_NODES + BNODES - 1) / BNODES)  // 391
#define SCAP 4608   // bucket capacity: mean 4096 + 8 sigma (sigma=64)
#define ACHUNK 4096 // edges per partA block
#define NB_PAD 512
#define SENTB 0xFFFFu
#define TSHIFT 13   // src tile = src >> 13 (8192 srcs = 1 MB of y per tile)
#define NTILES 13   // ceil(100000 / 8192)
#define RSTRIDE 72  // acci ints per node row: 8 blocks x 9 (8 data + 1 pad)
#define FPSCALE 1048576.0f      // 2^20 fixed-point scale
#define FPINV   (1.0f / 1048576.0f)

typedef _Float16 half8 __attribute__((ext_vector_type(8)));
typedef float f32x4 __attribute__((ext_vector_type(4)));

static __device__ __forceinline__ half8 as_half8(uint4 u) {
    union { uint4 u; half8 h; } x; x.u = u; return x.h;
}

// Blocks 0..7: pack W1 (MFMA B-layout, fp16 hi+lo).
// Block 8: v = W2@Wl, c = b2.Wl + bl, init bcur[b] = b*SCAP.
__global__ __launch_bounds__(256) void prep_kernel(
    const float* __restrict__ W1, const float* __restrict__ W2,
    const float* __restrict__ b2, const float* __restrict__ Wl,
    const float* __restrict__ bl,
    float* __restrict__ v, float* __restrict__ c, uint4* __restrict__ Wpk,
    int* __restrict__ bcur) {
    int t = threadIdx.x;
    if (blockIdx.x < 8) {
        // idx: bit10 = part (0=hi,1=lo), bits9..7 = cb, bit6 = kf, bits5..0 = lane
        int idx = blockIdx.x * 256 + t;
        int lane2 = idx & 63;
        int kf    = (idx >> 6) & 1;
        int cb    = (idx >> 7) & 7;
        int part  = (idx >> 10) & 1;
        union { uint4 u; unsigned short s[8]; } pk;
        #pragma unroll
        for (int j = 0; j < 8; ++j) {
            int k    = kf * 32 + (lane2 >> 4) * 8 + j;
            int colg = cb * 16 + (lane2 & 15);
            float w = W1[k * HID + colg];
            __half h = __float2half_rn(w);
            if (part) h = __float2half_rn(w - __half2float(h));
            pk.s[j] = __half_as_ushort(h);
        }
        Wpk[idx] = pk.u;
    } else {
        bcur[t] = t * SCAP;
        bcur[t + 256] = (t + 256) * SCAP;
        if (t < HID) {
            float acc = 0.f;
            for (int k = 0; k < OUT2; ++k) acc += W2[t * OUT2 + k] * Wl[k];
            v[t] = acc;
        } else if (t == HID) {
            float acc = bl[0];
            for (int k = 0; k < OUT2; ++k) acc += b2[k] * Wl[k];
            *c = acc;
        }
    }
}

// Pass A: LDS multi-split into padded dst-buckets; ONE reserve-atomic per
// bucket per block. Packed entry = (src<<8) | (dst&255).
__global__ __launch_bounds__(256) void partA_kernel(
    const int* __restrict__ src, const int* __restrict__ dst,
    int* __restrict__ bcur, unsigned int* __restrict__ ebuf, int E) {
    __shared__ unsigned int stage[ACHUNK];       // 16 KB
    __shared__ unsigned short sb[ACHUNK];        // 8 KB
    __shared__ int hist[NB_PAD];
    __shared__ int ocnt[NB_PAD];
    __shared__ int gbase[NB_PAD];
    __shared__ int cnt2[NB_PAD];
    int t = threadIdx.x;
    int base = blockIdx.x * ACHUNK;
    int total = E - base; if (total > ACHUNK) total = ACHUNK;

    hist[t] = 0; hist[t + 256] = 0;
    cnt2[t] = 0; cnt2[t + 256] = 0;
    __syncthreads();

    unsigned int pe[16];
    unsigned short bk[16];
    #pragma unroll
    for (int k = 0; k < 16; ++k) {
        int e = base + k * 256 + t;
        if (e < E) {
            int s = src[e], d = dst[e];
            pe[k] = ((unsigned int)s << 8) | (unsigned int)(d & (BNODES - 1));
            bk[k] = (unsigned short)(d >> BSHIFT);
            atomicAdd(&hist[bk[k]], 1);
        } else {
            bk[k] = SENTB;
        }
    }
    __syncthreads();
    ocnt[t] = hist[t]; ocnt[t + 256] = hist[t + 256];
    __syncthreads();
    for (int off = 1; off < NB_PAD; off <<= 1) {
        int v0 = (t >= off) ? hist[t - off] : 0;
        int v1 = hist[t + 256 - off];
        __syncthreads();
        hist[t] += v0; hist[t + 256] += v1;
        __syncthreads();
    }
    #pragma unroll
    for (int i = 0; i < 2; ++i) {
        int b = (t + i * 256 + blockIdx.x * 131) & (NB_PAD - 1);
        int cc = ocnt[b];
        if (cc > 0 && b < NBUCKETS) gbase[b] = atomicAdd(&bcur[b], cc);
    }
    __syncthreads();
    #pragma unroll
    for (int k = 0; k < 16; ++k) {
        if (bk[k] != SENTB) {
            int b = bk[k];
            int pos = (hist[b] - ocnt[b]) + atomicAdd(&cnt2[b], 1);
            stage[pos] = pe[k];
            sb[pos] = (unsigned short)b;
        }
    }
    __syncthreads();
    #pragma unroll
    for (int k = 0; k < 16; ++k) {
        int idx = k * 256 + t;
        if (idx < total) {
            int b = sb[idx];
            int lo = hist[b] - ocnt[b];
            ebuf[gbase[b] + (idx - lo)] = stage[idx];
        }
    }
}

// Pass B: per bucket: dl-histogram -> dinv + rs/re; node-major counting sort
// (csr keeps full entries src<<8|dl); tile-major perm of sorted positions;
// emits fp16 pre-scaled y rows.
__global__ __launch_bounds__(256) void partB_kernel(
    const int* __restrict__ bcur, unsigned int* __restrict__ csr,
    unsigned short* __restrict__ perm,
    int* __restrict__ rs, int* __restrict__ re, float* __restrict__ dinv,
    const float4* __restrict__ x4, __half2* __restrict__ y2,
    int n, int use_perm) {
    __shared__ int lcnt[BNODES];
    __shared__ int lscan[BNODES];
    __shared__ int lcur[BNODES];
    __shared__ float sdinv[BNODES];
    __shared__ unsigned int sbuf[SCAP];      // 18 KB
    __shared__ unsigned short psort[SCAP];   // 9 KB
    __shared__ int tcnt[16];
    __shared__ int tcur[16];
    int b = blockIdx.x, t = threadIdx.x;
    int node0 = b << BSHIFT;
    int nlocal = min(BNODES, n - node0);
    int base = b * SCAP;
    int cnt = bcur[b] - base;
    lcnt[t] = 0;
    if (t < 16) tcnt[t] = 0;
    __syncthreads();
    unsigned int er[SCAP / 256];
    #pragma unroll
    for (int k = 0; k < SCAP / 256; ++k) {
        int idx = k * 256 + t;
        er[k] = (idx < cnt) ? csr[base + idx] : 0xFFFFFFFFu;
        if (er[k] != 0xFFFFFFFFu) {
            atomicAdd(&lcnt[er[k] & (BNODES - 1)], 1);
            atomicAdd(&tcnt[er[k] >> (8 + TSHIFT)], 1);
        }
    }
    __syncthreads();
    int own = lcnt[t];
    sdinv[t] = rsqrtf((float)own + 1.0f);
    lscan[t] = own;
    __syncthreads();
    for (int off = 1; off < BNODES; off <<= 1) {
        int v = (t >= off) ? lscan[t - off] : 0;
        __syncthreads();
        lscan[t] += v;
        __syncthreads();
    }
    int excl = lscan[t] - own;
    lcur[t] = excl;
    if (t < nlocal) {
        rs[node0 + t] = base + excl;
        re[node0 + t] = base + excl + own;
        dinv[node0 + t] = sdinv[t];
    }
    if (t == 0) {
        int s = 0;
        #pragma unroll
        for (int i = 0; i < NTILES; ++i) { int cc = tcnt[i]; tcur[i] = s; s += cc; }
    }
    __syncthreads();
    // node-major dl-sort (full entries)
    #pragma unroll
    for (int k = 0; k < SCAP / 256; ++k) {
        unsigned int e = er[k];
        if (e != 0xFFFFFFFFu) {
            int p = atomicAdd(&lcur[(int)(e & (BNODES - 1))], 1);
            sbuf[p] = e;
        }
    }
    __syncthreads();
    // tile-major perm of sorted positions
    for (int p = t; p < cnt; p += 256) {
        int tt = (int)(sbuf[p] >> (8 + TSHIFT));
        int qpos = atomicAdd(&tcur[tt], 1);
        psort[qpos] = (unsigned short)p;
    }
    __syncthreads();
    for (int idx = t; idx < cnt; idx += 256) {
        csr[base + idx] = sbuf[idx];
        if (use_perm) perm[base + idx] = psort[idx];
    }
    // y emission (dinv[src]-prescaled fp16 rows)
    for (int i = t; i < nlocal * 16; i += 256) {
        int nl = i >> 4;
        int gi = (node0 + nl) * 16 + (i & 15);
        float di = sdinv[nl];
        float4 xv = x4[gi];
        y2[2 * gi]     = __floats2half2_rn(xv.x * di, xv.y * di);
        y2[2 * gi + 1] = __floats2half2_rn(xv.z * di, xv.w * di);
    }
}

// Fused layer 1: block = bucket (256 dst nodes), 391 blocks all resident.
// Edge order = perm (tile-major) -> live 1MB y-tile stays L2-hot per XCD.
// Gather shape: 64 lanes = 8 edges (q=lane>>3) x 8 uint4 cols (col=lane&7).
// Accumulate fixed-point int into acci at stride 72 (bank ~2-way) via native
// ds_add_u32. Then MFMA + epilogue.
__global__ __launch_bounds__(256) void fused1_kernel(
    const uint4* __restrict__ y4, const unsigned short* __restrict__ yh,
    const unsigned int* __restrict__ csr, const unsigned short* __restrict__ perm,
    const int* __restrict__ bcur, const float* __restrict__ dinv,
    const uint4* __restrict__ Wpk, const float* __restrict__ b1,
    const float* __restrict__ v, float* __restrict__ zz, int n) {
    __shared__ int acci[BNODES * RSTRIDE];   // 72 KB -> 2 blocks/CU, all resident
    int t = threadIdx.x;
    int lane = t & 63, wave = t >> 6;
    int q = lane >> 3, col = lane & 7;
    int b = blockIdx.x;
    int node0 = b << BSHIFT;
    int nlocal = min(BNODES, n - node0);
    int base = b * SCAP;
    int cnt = bcur[b] - base;

    // self-loop init (fixed-point): acc[r][f] = y[node0+r][f]
    for (int r = wave; r < BNODES; r += 4) {
        float vv = 0.f;
        if (r < nlocal) vv = __half2float(__ushort_as_half(yh[(node0 + r) * 64 + lane]));
        acci[r * RSTRIDE + (lane >> 3) * 9 + (lane & 7)] = __float2int_rn(vv * FPSCALE);
    }
    __syncthreads();

    // edge accumulation in perm (tile) order; waves interleave 64-edge chunks.
    int nrounds = (cnt + 255) >> 8;
    for (int r = 0; r < nrounds; ++r) {
        int pidx = r * 256 + wave * 64 + lane;
        unsigned int ee = 0xFFFFFFFFu;
        if (pidx < cnt) {
            int p = perm ? (int)perm[base + pidx] : pidx;
            ee = csr[base + p];
        }
        uint4 u[8];
        int dl[8];
        #pragma unroll
        for (int g = 0; g < 8; ++g) {
            unsigned int e = __shfl(ee, g * 8 + q, 64);
            bool valid = (e != 0xFFFFFFFFu);
            int srow = valid ? (int)(e >> 8) : 0;
            dl[g] = (int)(e & 255u);           // 255 for invalid: safe row
            u[g] = y4[srow * 8 + col];
            if (!valid) u[g] = (uint4){0u, 0u, 0u, 0u};  // adds int 0 = no-op
        }
        #pragma unroll
        for (int g = 0; g < 8; ++g) {
            const __half* hp = (const __half*)&u[g];
            int* rowp = &acci[dl[g] * RSTRIDE + col * 9];
            #pragma unroll
            for (int j = 0; j < 8; ++j)
                atomicAdd(&rowp[j],
                          __float2int_rn(__half2float(hp[j]) * FPSCALE));
        }
    }
    __syncthreads();

    // MFMA + epilogue: each wave handles 4 sub-tiles of 16 nodes.
    int mm = lane & 15, kq = lane >> 4;
    for (int i = 0; i < 4; ++i) {
        int st = wave * 4 + i;
        int row = st * 16 + mm;
        float dis = ((row < nlocal) ? dinv[node0 + row] : 0.f) * FPINV;
        const int* ap = &acci[row * RSTRIDE];
        half8 A0, A1;
        #pragma unroll
        for (int j = 0; j < 8; ++j) {
            A0[j] = (_Float16)(dis * (float)ap[kq * 9 + j]);
            A1[j] = (_Float16)(dis * (float)ap[(4 + kq) * 9 + j]);
        }
        f32x4 acc[8];
        #pragma unroll
        for (int cb = 0; cb < 8; ++cb) acc[cb] = (f32x4){0.f, 0.f, 0.f, 0.f};
        #pragma unroll
        for (int cb = 0; cb < 8; ++cb) {
            half8 bh0 = as_half8(Wpk[(cb * 2 + 0) * 64 + lane]);
            half8 bh1 = as_half8(Wpk[(cb * 2 + 1) * 64 + lane]);
            half8 bl0 = as_half8(Wpk[1024 + (cb * 2 + 0) * 64 + lane]);
            half8 bl1 = as_half8(Wpk[1024 + (cb * 2 + 1) * 64 + lane]);
            acc[cb] = __builtin_amdgcn_mfma_f32_16x16x32_f16(A0, bh0, acc[cb], 0, 0, 0);
            acc[cb] = __builtin_amdgcn_mfma_f32_16x16x32_f16(A1, bh1, acc[cb], 0, 0, 0);
            acc[cb] = __builtin_amdgcn_mfma_f32_16x16x32_f16(A0, bl0, acc[cb], 0, 0, 0);
            acc[cb] = __builtin_amdgcn_mfma_f32_16x16x32_f16(A1, bl1, acc[cb], 0, 0, 0);
        }
        float zp[4] = {0.f, 0.f, 0.f, 0.f};
        #pragma unroll
        for (int cb = 0; cb < 8; ++cb) {
            int colg = cb * 16 + mm;
            float bb1 = b1[colg], vv = v[colg];
            #pragma unroll
            for (int rr = 0; rr < 4; ++rr) {
                float h = acc[cb][rr] + bb1;
                h = fmaxf(h, 0.f);
                zp[rr] += h * vv;
            }
        }
        #pragma unroll
        for (int off = 1; off < 16; off <<= 1) {
            #pragma unroll
            for (int rr = 0; rr < 4; ++rr) zp[rr] += __shfl_xor(zp[rr], off, 64);
        }
        if (mm == 0) {
            int nb = st * 16 + kq * 4;
            #pragma unroll
            for (int rr = 0; rr < 4; ++rr)
                if (nb + rr < nlocal)
                    zz[node0 + nb + rr] = dinv[node0 + nb + rr] * zp[rr];
        }
    }
}

// Layer 2 (collapsed): out[i] = c + dinv[i]*(zz[i] + sum_in zz[s]).
// 8 lanes/node, 2 pipelined slots per lane (csr prefetched a round ahead).
__global__ void out_kernel(const int* __restrict__ rs, const int* __restrict__ re,
                           const unsigned int* __restrict__ csr,
                           const float* __restrict__ dinv, const float* __restrict__ zz,
                           const float* __restrict__ c, float* __restrict__ out, int n) {
    int tid = blockIdx.x * blockDim.x + threadIdx.x;
    int node = tid >> 3;
    int sub = tid & 7;
    if (node >= n) return;
    int beg = rs[node], end = re[node];
    float acc = 0.f;
    int p = beg + sub;
    int s0 = (p < end) ? (int)(csr[p] >> 8) : -1;
    int s1 = (p + 8 < end) ? (int)(csr[p + 8] >> 8) : -1;
    for (int cb = beg; cb < end; cb += 16) {
        int c0 = s0, c1 = s1;
        int np = cb + 16 + sub;
        s0 = (np < end) ? (int)(csr[np] >> 8) : -1;
        s1 = (np + 8 < end) ? (int)(csr[np + 8] >> 8) : -1;
        float z0 = (c0 >= 0) ? zz[c0] : 0.f;
        float z1 = (c1 >= 0) ? zz[c1] : 0.f;
        acc += z0 + z1;
    }
    acc += __shfl_xor(acc, 1, 64);
    acc += __shfl_xor(acc, 2, 64);
    acc += __shfl_xor(acc, 4, 64);
    if (sub == 0) out[node] = c[0] + dinv[node] * (acc + zz[node]);
}

extern "C" void kernel_launch(void* const* d_in, const int* in_sizes, int n_in,
                              void* d_out, int out_size, void* d_ws, size_t ws_size,
                              hipStream_t stream) {
    const float* x  = (const float*)d_in[0];
    const int*   ei = (const int*)d_in[1];
    const float* W1 = (const float*)d_in[2];
    const float* b1 = (const float*)d_in[3];
    const float* W2 = (const float*)d_in[4];
    const float* b2 = (const float*)d_in[5];
    const float* Wl = (const float*)d_in[6];
    const float* bl = (const float*)d_in[7];
    float* out = (float*)d_out;

    int E = in_sizes[1] / 2;
    const int* src = ei;
    const int* dst = ei + E;

    float* ws      = (float*)d_ws;
    float* dinv    = ws;                        // N
    int*   rs      = (int*)(dinv + N_NODES);    // N
    int*   re      = rs + N_NODES;              // N
    float* zz      = (float*)(re + N_NODES);    // N
    float* v       = zz + N_NODES;              // 128
    float* c       = v + HID;                   // 4
    int*   bcur    = (int*)(c + 4);             // 512
    int*   csr     = bcur + 512;                // NBUCKETS*SCAP ints
    uint4* Wpk     = (uint4*)(csr + (size_t)NBUCKETS * SCAP);  // 2048 uint4
    __half* y      = (__half*)((float*)Wpk + 8192);            // N*64 halves
    unsigned short* perm = (unsigned short*)(y + (size_t)N_NODES * 64); // NBUCKETS*SCAP ushort

    size_t used_floats = (size_t)N_NODES * 4 + HID + 4 + 512
                       + (size_t)NBUCKETS * SCAP + 8192
                       + (size_t)N_NODES * 32               // y
                       + ((size_t)NBUCKETS * SCAP + 1) / 2; // perm
    int use_perm = (ws_size >= used_floats * 4) ? 1 : 0;

    int nchunks = (E + ACHUNK - 1) / ACHUNK;   // 391

    prep_kernel<<<9, 256, 0, stream>>>(W1, W2, b2, Wl, bl, v, c, Wpk, bcur);
    partA_kernel<<<nchunks, 256, 0, stream>>>(src, dst, bcur, (unsigned int*)csr, E);
    partB_kernel<<<NBUCKETS, 256, 0, stream>>>(
        bcur, (unsigned int*)csr, perm, rs, re, dinv,
        (const float4*)x, (__half2*)y, N_NODES, use_perm);
    fused1_kernel<<<NBUCKETS, 256, 0, stream>>>(
        (const uint4*)y, (const unsigned short*)y, (const unsigned int*)csr,
        use_perm ? perm : (const unsigned short*)nullptr,
        bcur, dinv, Wpk, b1, v, zz, N_NODES);
    out_kernel<<<(N_NODES * 8 + 255) / 256, 256, 0, stream>>>(
        rs, re, (const unsigned int*)csr, dinv, zz, c, out, N_NODES);
}

// Round 5
// 178.008 us; speedup vs baseline: 4.9520x; 1.3498x over previous
//
#include <hip/hip_runtime.h>
#include <hip/hip_fp16.h>

// GCN 2-layer, N=100000, F=64, H=128, O=100, out [N,1] fp32.
// out = agg(relu(agg(x)@W1 + b1) . (W2@Wl)) + (b2@Wl + bl)
// partA: multi-split edges into padded dst-buckets (entry = src<<7|dl, 128/bucket).
// partB: dl-histogram -> dinv; 13-bin TILE-major sort of csr (tile = src>>13 =
//        1MB of y); emits int16 fixed-point (2^12) dinv-prescaled y rows.
// fused1: 782-block all-resident grid (4 blocks/CU, 16 waves/CU); walks csr in
//        tile order (live 1MB y-tile L2-hot per XCD; verified 60MB fetch r4);
//        int16 gather rows -> sext -> native ds_add_u32 into stride-76 LDS
//        (12*dl mod 32: within-col 8-bank spread). Edge words prefetched one
//        round ahead. Then MFMA + fused layer-2-weight epilogue.
// out: per-bucket tile-major zz gather (32KB L1 window) + int LDS accumulate.
// fp32 LDS atomicAdd is a ~440cyc CAS loop on this toolchain (rounds 1-3);
// int LDS atomics are native-speed — everything accumulates in fixed-point.

#define N_NODES 100000
#define F_IN 64
#define HID 128
#define OUT2 100
#define BSHIFT 7
#define BNODES 128
#define NBUCKETS ((N_NODES + BNODES - 1) / BNODES)  // 782
#define SCAP 2560   // bucket capacity: mean 2046 + ~11 sigma
#define ACHUNK 4096 // edges per partA block
#define NB_PAD 1024
#define SENTB 0xFFFFu
#define SENTE 0xFFFFFFFFu
#define TSHIFT 13   // src tile = src >> 13 (8192 srcs = 1 MB of y per tile)
#define NTILES 13   // ceil(100000 / 8192)
#define RSTRIDE 76  // acci ints per node row: 8 blocks x 9 + 4 pad (12*dl mod 32)
#define YSCALE 4096.0f        // y int16 fixed-point 2^12
#define YINV   (1.0f / 4096.0f)
#define ZSCALE 8192.0f        // zz accumulation fixed-point 2^13
#define ZINV   (1.0f / 8192.0f)

typedef _Float16 half8 __attribute__((ext_vector_type(8)));
typedef float f32x4 __attribute__((ext_vector_type(4)));

static __device__ __forceinline__ half8 as_half8(uint4 u) {
    union { uint4 u; half8 h; } x; x.u = u; return x.h;
}

// Blocks 0..7: pack W1 (MFMA B-layout, fp16 hi+lo).
// Block 8: v = W2@Wl, c = b2.Wl + bl, init bcur[b] = b*SCAP.
__global__ __launch_bounds__(256) void prep_kernel(
    const float* __restrict__ W1, const float* __restrict__ W2,
    const float* __restrict__ b2, const float* __restrict__ Wl,
    const float* __restrict__ bl,
    float* __restrict__ v, float* __restrict__ c, uint4* __restrict__ Wpk,
    int* __restrict__ bcur) {
    int t = threadIdx.x;
    if (blockIdx.x < 8) {
        // idx: bit10 = part (0=hi,1=lo), bits9..7 = cb, bit6 = kf, bits5..0 = lane
        int idx = blockIdx.x * 256 + t;
        int lane2 = idx & 63;
        int kf    = (idx >> 6) & 1;
        int cb    = (idx >> 7) & 7;
        int part  = (idx >> 10) & 1;
        union { uint4 u; unsigned short s[8]; } pk;
        #pragma unroll
        for (int j = 0; j < 8; ++j) {
            int k    = kf * 32 + (lane2 >> 4) * 8 + j;
            int colg = cb * 16 + (lane2 & 15);
            float w = W1[k * HID + colg];
            __half h = __float2half_rn(w);
            if (part) h = __float2half_rn(w - __half2float(h));
            pk.s[j] = __half_as_ushort(h);
        }
        Wpk[idx] = pk.u;
    } else {
        #pragma unroll
        for (int i = 0; i < 4; ++i) bcur[t + i * 256] = (t + i * 256) * SCAP;
        if (t < HID) {
            float acc = 0.f;
            for (int k = 0; k < OUT2; ++k) acc += W2[t * OUT2 + k] * Wl[k];
            v[t] = acc;
        } else if (t == HID) {
            float acc = bl[0];
            for (int k = 0; k < OUT2; ++k) acc += b2[k] * Wl[k];
            *c = acc;
        }
    }
}

// Pass A: LDS multi-split into padded dst-buckets; ONE reserve-atomic per
// bucket per block. Packed entry = (src<<7) | (dst&127).
__global__ __launch_bounds__(256) void partA_kernel(
    const int* __restrict__ src, const int* __restrict__ dst,
    int* __restrict__ bcur, unsigned int* __restrict__ ebuf, int E) {
    __shared__ unsigned int stage[ACHUNK];       // 16 KB
    __shared__ unsigned short sb[ACHUNK];        // 8 KB
    __shared__ int hist[NB_PAD];                 // 4 KB each
    __shared__ int ocnt[NB_PAD];
    __shared__ int gbase[NB_PAD];
    __shared__ int cnt2[NB_PAD];
    int t = threadIdx.x;
    int base = blockIdx.x * ACHUNK;
    int total = E - base; if (total > ACHUNK) total = ACHUNK;

    #pragma unroll
    for (int i = 0; i < 4; ++i) { hist[t + i * 256] = 0; cnt2[t + i * 256] = 0; }
    __syncthreads();

    unsigned int pe[16];
    unsigned short bk[16];
    #pragma unroll
    for (int k = 0; k < 16; ++k) {
        int e = base + k * 256 + t;
        if (e < E) {
            int s = src[e], d = dst[e];
            pe[k] = ((unsigned int)s << BSHIFT) | (unsigned int)(d & (BNODES - 1));
            bk[k] = (unsigned short)(d >> BSHIFT);
            atomicAdd(&hist[bk[k]], 1);
        } else {
            bk[k] = SENTB;
        }
    }
    __syncthreads();
    #pragma unroll
    for (int i = 0; i < 4; ++i) ocnt[t + i * 256] = hist[t + i * 256];
    __syncthreads();
    for (int off = 1; off < NB_PAD; off <<= 1) {
        int v4[4];
        #pragma unroll
        for (int i = 0; i < 4; ++i) {
            int p = t + i * 256;
            v4[i] = (p >= off) ? hist[p - off] : 0;
        }
        __syncthreads();
        #pragma unroll
        for (int i = 0; i < 4; ++i) hist[t + i * 256] += v4[i];
        __syncthreads();
    }
    #pragma unroll
    for (int i = 0; i < 4; ++i) {
        int b = (t + i * 256 + blockIdx.x * 131) & (NB_PAD - 1);
        int cc = ocnt[b];
        if (cc > 0 && b < NBUCKETS) gbase[b] = atomicAdd(&bcur[b], cc);
    }
    __syncthreads();
    #pragma unroll
    for (int k = 0; k < 16; ++k) {
        if (bk[k] != SENTB) {
            int b = bk[k];
            int pos = (hist[b] - ocnt[b]) + atomicAdd(&cnt2[b], 1);
            stage[pos] = pe[k];
            sb[pos] = (unsigned short)b;
        }
    }
    __syncthreads();
    #pragma unroll
    for (int k = 0; k < 16; ++k) {
        int idx = k * 256 + t;
        if (idx < total) {
            int b = sb[idx];
            int lo = hist[b] - ocnt[b];
            ebuf[gbase[b] + (idx - lo)] = stage[idx];
        }
    }
}

// Pass B: per bucket: dl-histogram -> dinv; 13-bin TILE-major counting sort
// (in-place, full entries src<<7|dl); emits int16 (2^12) pre-scaled y rows.
__global__ __launch_bounds__(256) void partB_kernel(
    const int* __restrict__ bcur, unsigned int* __restrict__ csr,
    float* __restrict__ dinv,
    const float4* __restrict__ x4, uint2* __restrict__ y2, int n) {
    __shared__ int lcnt[BNODES];
    __shared__ float sdinv[BNODES];
    __shared__ int tcnt[16];
    __shared__ int tcur[16];
    __shared__ unsigned int sbuf[SCAP];      // 10 KB
    int b = blockIdx.x, t = threadIdx.x;
    int node0 = b << BSHIFT;
    int nlocal = min(BNODES, n - node0);
    int base = b * SCAP;
    int cnt = bcur[b] - base;
    if (t < BNODES) lcnt[t] = 0;
    if (t < 16) tcnt[t] = 0;
    __syncthreads();
    unsigned int er[SCAP / 256];
    #pragma unroll
    for (int k = 0; k < SCAP / 256; ++k) {
        int idx = k * 256 + t;
        er[k] = (idx < cnt) ? csr[base + idx] : SENTE;
        if (er[k] != SENTE) {
            atomicAdd(&lcnt[er[k] & (BNODES - 1)], 1);
            atomicAdd(&tcnt[er[k] >> (BSHIFT + TSHIFT)], 1);
        }
    }
    __syncthreads();
    if (t < BNODES) {
        float sd = rsqrtf((float)lcnt[t] + 1.0f);
        sdinv[t] = sd;
        if (t < nlocal) dinv[node0 + t] = sd;
    }
    if (t == 0) {
        int s = 0;
        #pragma unroll
        for (int i = 0; i < NTILES; ++i) { tcur[i] = s; s += tcnt[i]; }
    }
    __syncthreads();
    #pragma unroll
    for (int k = 0; k < SCAP / 256; ++k) {
        unsigned int e = er[k];
        if (e != SENTE) {
            int p = atomicAdd(&tcur[e >> (BSHIFT + TSHIFT)], 1);
            sbuf[p] = e;
        }
    }
    __syncthreads();
    for (int idx = t; idx < cnt; idx += 256) csr[base + idx] = sbuf[idx];
    // y emission: int16 fixed-point, dinv[src]-prescaled
    for (int i = t; i < nlocal * 16; i += 256) {
        int nl = i >> 4;
        int gi = (node0 + nl) * 16 + (i & 15);
        float sc = sdinv[nl] * YSCALE;
        float4 xv = x4[gi];
        int a0 = __float2int_rn(xv.x * sc);
        int a1 = __float2int_rn(xv.y * sc);
        int a2 = __float2int_rn(xv.z * sc);
        int a3 = __float2int_rn(xv.w * sc);
        uint2 pk;
        pk.x = ((unsigned int)a0 & 0xFFFFu) | ((unsigned int)a1 << 16);
        pk.y = ((unsigned int)a2 & 0xFFFFu) | ((unsigned int)a3 << 16);
        y2[gi] = pk;
    }
}

// Fused layer 1: block = bucket (128 dst nodes), 782 blocks, 4/CU all resident.
// csr is tile-major -> live 1MB y-tile stays L2-hot per XCD.
// Gather: 64 lanes = 8 edges (q=lane>>3) x 8 int4 cols (col=lane&7); edge word
// prefetched one round ahead. Accumulate int16-sext into acci stride 76 via
// native ds_add_u32 (bank = (12dl+9col+j)&31: col-classes disjoint, within-col
// dl mod 8 -> ~2.5-way). Then MFMA + epilogue.
__global__ __launch_bounds__(256, 4) void fused1_kernel(
    const int4* __restrict__ y4, const short* __restrict__ yh,
    const unsigned int* __restrict__ csr, const int* __restrict__ bcur,
    const float* __restrict__ dinv, const uint4* __restrict__ Wpk,
    const float* __restrict__ b1, const float* __restrict__ v,
    float* __restrict__ zz, int n) {
    __shared__ int acci[BNODES * RSTRIDE];   // 38912 B -> 4 blocks/CU
    int t = threadIdx.x;
    int lane = t & 63, wave = t >> 6;
    int q = lane >> 3, col = lane & 7;
    int b = blockIdx.x;
    int node0 = b << BSHIFT;
    int nlocal = min(BNODES, n - node0);
    int base = b * SCAP;
    int cnt = bcur[b] - base;

    // self-loop init: acc[r][f] = y[node0+r][f] (int16, already dinv-prescaled)
    for (int r = wave; r < BNODES; r += 4) {
        int vv = 0;
        if (r < nlocal) vv = (int)yh[(node0 + r) * 64 + lane];
        acci[r * RSTRIDE + (lane >> 3) * 9 + (lane & 7)] = vv;
    }
    __syncthreads();

    // edge accumulation in tile order; waves interleave 64-edge chunks;
    // edge words prefetched one round ahead.
    int nr = (cnt + 255) >> 8;
    int p0 = wave * 64 + lane;
    unsigned int ee = (p0 < cnt) ? csr[base + p0] : SENTE;
    for (int r = 0; r < nr; ++r) {
        int pn = (r + 1) * 256 + wave * 64 + lane;
        unsigned int ee_n = (pn < cnt) ? csr[base + pn] : SENTE;
        int4 u[8];
        int dl[8];
        #pragma unroll
        for (int g = 0; g < 8; ++g) {
            unsigned int e = __shfl(ee, g * 8 + q, 64);
            bool valid = (e != SENTE);
            int srow = valid ? (int)(e >> BSHIFT) : 0;
            dl[g] = (int)(e & (BNODES - 1));   // 127 for invalid: safe row
            u[g] = y4[srow * 8 + col];
            if (!valid) u[g] = (int4){0, 0, 0, 0};  // adds int 0 = no-op
        }
        #pragma unroll
        for (int g = 0; g < 8; ++g) {
            int* rowp = &acci[dl[g] * RSTRIDE + col * 9];
            const int* up = (const int*)&u[g];
            #pragma unroll
            for (int j = 0; j < 4; ++j) {
                int d = up[j];
                atomicAdd(&rowp[2 * j],     (d << 16) >> 16);
                atomicAdd(&rowp[2 * j + 1], d >> 16);
            }
        }
        ee = ee_n;
    }
    __syncthreads();

    // MFMA + epilogue: each wave handles 2 sub-tiles of 16 nodes.
    int mm = lane & 15, kq = lane >> 4;
    for (int i = 0; i < 2; ++i) {
        int st = wave * 2 + i;
        int row = st * 16 + mm;
        float dis = ((row < nlocal) ? dinv[node0 + row] : 0.f) * YINV;
        const int* ap = &acci[row * RSTRIDE];
        half8 A0, A1;
        #pragma unroll
        for (int j = 0; j < 8; ++j) {
            A0[j] = (_Float16)(dis * (float)ap[kq * 9 + j]);
            A1[j] = (_Float16)(dis * (float)ap[(4 + kq) * 9 + j]);
        }
        f32x4 acc[8];
        #pragma unroll
        for (int cb = 0; cb < 8; ++cb) acc[cb] = (f32x4){0.f, 0.f, 0.f, 0.f};
        #pragma unroll
        for (int cb = 0; cb < 8; ++cb) {
            half8 bh0 = as_half8(Wpk[(cb * 2 + 0) * 64 + lane]);
            half8 bh1 = as_half8(Wpk[(cb * 2 + 1) * 64 + lane]);
            half8 bl0 = as_half8(Wpk[1024 + (cb * 2 + 0) * 64 + lane]);
            half8 bl1 = as_half8(Wpk[1024 + (cb * 2 + 1) * 64 + lane]);
            acc[cb] = __builtin_amdgcn_mfma_f32_16x16x32_f16(A0, bh0, acc[cb], 0, 0, 0);
            acc[cb] = __builtin_amdgcn_mfma_f32_16x16x32_f16(A1, bh1, acc[cb], 0, 0, 0);
            acc[cb] = __builtin_amdgcn_mfma_f32_16x16x32_f16(A0, bl0, acc[cb], 0, 0, 0);
            acc[cb] = __builtin_amdgcn_mfma_f32_16x16x32_f16(A1, bl1, acc[cb], 0, 0, 0);
        }
        float zp[4] = {0.f, 0.f, 0.f, 0.f};
        #pragma unroll
        for (int cb = 0; cb < 8; ++cb) {
            int colg = cb * 16 + mm;
            float bb1 = b1[colg], vv = v[colg];
            #pragma unroll
            for (int rr = 0; rr < 4; ++rr) {
                float h = acc[cb][rr] + bb1;
                h = fmaxf(h, 0.f);
                zp[rr] += h * vv;
            }
        }
        #pragma unroll
        for (int off = 1; off < 16; off <<= 1) {
            #pragma unroll
            for (int rr = 0; rr < 4; ++rr) zp[rr] += __shfl_xor(zp[rr], off, 64);
        }
        if (mm == 0) {
            int nb = st * 16 + kq * 4;
            #pragma unroll
            for (int rr = 0; rr < 4; ++rr)
                if (nb + rr < nlocal)
                    zz[node0 + nb + rr] = dinv[node0 + nb + rr] * zp[rr];
        }
    }
}

// Layer 2 (collapsed): per-bucket tile-major zz gather (32KB L1 window) +
// int fixed-point LDS accumulate. out[i] = c + dinv[i]*(zz[i] + sum_in zz[s]).
__global__ __launch_bounds__(256) void out_kernel(
    const int* __restrict__ bcur, const unsigned int* __restrict__ csr,
    const float* __restrict__ dinv, const float* __restrict__ zz,
    const float* __restrict__ c, float* __restrict__ out, int n) {
    __shared__ int acc2[BNODES];
    int b = blockIdx.x, t = threadIdx.x;
    int node0 = b << BSHIFT;
    int nlocal = min(BNODES, n - node0);
    int base = b * SCAP;
    int cnt = bcur[b] - base;
    if (t < BNODES) acc2[t] = 0;
    __syncthreads();
    for (int idx = t; idx < cnt; idx += 256) {
        unsigned int e = csr[base + idx];
        float z = zz[e >> BSHIFT];
        atomicAdd(&acc2[e & (BNODES - 1)], __float2int_rn(z * ZSCALE));
    }
    __syncthreads();
    if (t < nlocal) {
        int node = node0 + t;
        out[node] = c[0] + dinv[node] * ((float)acc2[t] * ZINV + zz[node]);
    }
}

extern "C" void kernel_launch(void* const* d_in, const int* in_sizes, int n_in,
                              void* d_out, int out_size, void* d_ws, size_t ws_size,
                              hipStream_t stream) {
    const float* x  = (const float*)d_in[0];
    const int*   ei = (const int*)d_in[1];
    const float* W1 = (const float*)d_in[2];
    const float* b1 = (const float*)d_in[3];
    const float* W2 = (const float*)d_in[4];
    const float* b2 = (const float*)d_in[5];
    const float* Wl = (const float*)d_in[6];
    const float* bl = (const float*)d_in[7];
    float* out = (float*)d_out;

    int E = in_sizes[1] / 2;
    const int* src = ei;
    const int* dst = ei + E;

    float* ws      = (float*)d_ws;
    float* dinv    = ws;                        // N
    float* zz      = dinv + N_NODES;            // N
    float* v       = zz + N_NODES;              // 128
    float* c       = v + HID;                   // 4
    int*   bcur    = (int*)(c + 4);             // 1024
    int*   csr     = bcur + NB_PAD;             // NBUCKETS*SCAP ints
    uint4* Wpk     = (uint4*)(csr + (size_t)NBUCKETS * SCAP);  // 2048 uint4
    short* y       = (short*)((float*)Wpk + 8192);             // N*64 int16

    int nchunks = (E + ACHUNK - 1) / ACHUNK;   // 391

    prep_kernel<<<9, 256, 0, stream>>>(W1, W2, b2, Wl, bl, v, c, Wpk, bcur);
    partA_kernel<<<nchunks, 256, 0, stream>>>(src, dst, bcur, (unsigned int*)csr, E);
    partB_kernel<<<NBUCKETS, 256, 0, stream>>>(
        bcur, (unsigned int*)csr, dinv, (const float4*)x, (uint2*)y, N_NODES);
    fused1_kernel<<<NBUCKETS, 256, 0, stream>>>(
        (const int4*)y, (const short*)y, (const unsigned int*)csr,
        bcur, dinv, Wpk, b1, v, zz, N_NODES);
    out_kernel<<<NBUCKETS, 256, 0, stream>>>(
        bcur, (const unsigned int*)csr, dinv, zz, c, out, N_NODES);
}